// Round 4
// baseline (175.023 us; speedup 1.0000x reference)
//
#include <hip/hip_runtime.h>

#define LL 2048
#define DD 64
#define BB 8
#define EPSF 1e-8f

// ws layout (bf16 elements): [q_hi | y_hi | q_lo | y_lo], 2 MB each = 8 MB total.
#define NELEM ((size_t)BB * LL * DD)

typedef short bf16x8 __attribute__((ext_vector_type(8)));
typedef float f32x4 __attribute__((ext_vector_type(4)));

__device__ __forceinline__ ushort f2bf(float f) {  // RNE float->bf16
    uint u = __float_as_uint(f);
    return (ushort)((u + 0x7fffu + ((u >> 16) & 1u)) >> 16);
}
__device__ __forceinline__ float bf2f(ushort h) {
    return __uint_as_float((uint)h << 16);
}

// Normalize rows of q and y (fp32), split into bf16 hi + lo. 32 rows/block, 8 lanes/row.
__global__ __launch_bounds__(256) void norm_split_kernel(
    const float* __restrict__ q, const float* __restrict__ y,
    ushort* __restrict__ ws) {
    const int row   = blockIdx.x * 32 + (threadIdx.x >> 3);  // 0..16383
    const int oct   = threadIdx.x & 7;
    const int which = blockIdx.y;  // 0=q, 1=y
    const float* src = which ? y : q;
    ushort* hi = ws + (size_t)which * NELEM;
    ushort* lo = ws + 2 * NELEM + (size_t)which * NELEM;

    const float* g = src + (size_t)row * DD;
    float4 v0 = *reinterpret_cast<const float4*>(g + oct * 4);
    float4 v1 = *reinterpret_cast<const float4*>(g + 32 + oct * 4);
    float ss = v0.x*v0.x + v0.y*v0.y + v0.z*v0.z + v0.w*v0.w
             + v1.x*v1.x + v1.y*v1.y + v1.z*v1.z + v1.w*v1.w;
    ss += __shfl_xor(ss, 1);
    ss += __shfl_xor(ss, 2);
    ss += __shfl_xor(ss, 4);
    const float sc = 1.0f / fmaxf(sqrtf(ss), EPSF);

    const float f[8] = {v0.x*sc, v0.y*sc, v0.z*sc, v0.w*sc,
                        v1.x*sc, v1.y*sc, v1.z*sc, v1.w*sc};
    ushort h[8], l8[8];
    #pragma unroll
    for (int i = 0; i < 8; ++i) {
        h[i]  = f2bf(f[i]);
        l8[i] = f2bf(f[i] - bf2f(h[i]));
    }
    const size_t base = (size_t)row * DD + oct * 4;
    *reinterpret_cast<ushort4*>(hi + base)      = make_ushort4(h[0], h[1], h[2], h[3]);
    *reinterpret_cast<ushort4*>(hi + base + 32) = make_ushort4(h[4], h[5], h[6], h[7]);
    *reinterpret_cast<ushort4*>(lo + base)      = make_ushort4(l8[0], l8[1], l8[2], l8[3]);
    *reinterpret_cast<ushort4*>(lo + base + 32) = make_ushort4(l8[4], l8[5], l8[6], l8[7]);
}

// One block = (batch b, 32-q-row strip). XCD-pinned: 1-D grid, b = blockIdx.x & 7 so
// all 64 blocks of a batch land on ONE XCD -> its 1 MB y-panel stays L2-resident.
// att stores are nontemporal so the 134 MB write stream doesn't evict the y-panel.
// Operands SWAPPED: A-frag = y rows (M), B-frag = q rows (N), so D col=lane&15 = q row,
// row=kg*4+j = y col -> float4 stores along output cols, per-lane row-max.
__global__ __launch_bounds__(256, 2) void att_mfma_kernel(
    const ushort* __restrict__ ws, float* __restrict__ out) {
    const int b       = blockIdx.x & 7;   // batch -> XCD pinning
    const int rowBase = (blockIdx.x >> 3) * 32;
    const int t  = threadIdx.x;
    const int w  = t >> 6;
    const int l  = t & 63;
    const int ln = l & 15;   // q row within 16-subtile
    const int kg = l >> 4;   // k-group; in D: y-col group of 4

    const ushort* qh = ws;
    const ushort* yh = ws + NELEM;
    const ushort* ql = ws + 2 * NELEM;
    const ushort* yl = ws + 3 * NELEM;

    // B fragments (q rows): loaded once, reused across all col tiles.
    bf16x8 qhf[2][2], qlf[2][2];
    #pragma unroll
    for (int mq = 0; mq < 2; ++mq)
        #pragma unroll
        for (int kk = 0; kk < 2; ++kk) {
            const size_t off =
                ((size_t)(b * LL + rowBase + mq * 16 + ln)) * DD + kk * 32 + kg * 8;
            qhf[mq][kk] = *reinterpret_cast<const bf16x8*>(qh + off);
            qlf[mq][kk] = *reinterpret_cast<const bf16x8*>(ql + off);
        }

    float rmax[2] = {-1e30f, -1e30f};  // per-lane: q row = rowBase + mq*16 + ln

    bf16x8 yh0[4][2], yl0[4][2], yh1[4][2], yl1[4][2];

#define LOADY(DH, DL, CT) do {                                                   \
    const int colBase_ = (CT) * 256 + w * 64;                                    \
    _Pragma("unroll")                                                            \
    for (int ny = 0; ny < 4; ++ny) {                                             \
        _Pragma("unroll")                                                        \
        for (int kk = 0; kk < 2; ++kk) {                                         \
            const size_t off_ =                                                  \
                ((size_t)(b * LL + colBase_ + ny * 16 + ln)) * DD + kk * 32 + kg * 8; \
            DH[ny][kk] = *reinterpret_cast<const bf16x8*>(yh + off_);            \
            DL[ny][kk] = *reinterpret_cast<const bf16x8*>(yl + off_);            \
        }                                                                        \
    }                                                                            \
} while (0)

#define COMPSTORE(SH, SL, CT) do {                                               \
    const int colBase_ = (CT) * 256 + w * 64;                                    \
    f32x4 acc[2][4];                                                             \
    _Pragma("unroll")                                                            \
    for (int mq = 0; mq < 2; ++mq)                                               \
        _Pragma("unroll")                                                        \
        for (int ny = 0; ny < 4; ++ny)                                           \
            acc[mq][ny] = (f32x4){0.f, 0.f, 0.f, 0.f};                           \
    _Pragma("unroll")                                                            \
    for (int kk = 0; kk < 2; ++kk)                                               \
        _Pragma("unroll")                                                        \
        for (int mq = 0; mq < 2; ++mq)                                           \
            _Pragma("unroll")                                                    \
            for (int ny = 0; ny < 4; ++ny)                                       \
                acc[mq][ny] = __builtin_amdgcn_mfma_f32_16x16x32_bf16(           \
                    SL[ny][kk], qhf[mq][kk], acc[mq][ny], 0, 0, 0);              \
    _Pragma("unroll")                                                            \
    for (int kk = 0; kk < 2; ++kk)                                               \
        _Pragma("unroll")                                                        \
        for (int mq = 0; mq < 2; ++mq)                                           \
            _Pragma("unroll")                                                    \
            for (int ny = 0; ny < 4; ++ny)                                       \
                acc[mq][ny] = __builtin_amdgcn_mfma_f32_16x16x32_bf16(           \
                    SH[ny][kk], qlf[mq][kk], acc[mq][ny], 0, 0, 0);              \
    _Pragma("unroll")                                                            \
    for (int kk = 0; kk < 2; ++kk)                                               \
        _Pragma("unroll")                                                        \
        for (int mq = 0; mq < 2; ++mq)                                           \
            _Pragma("unroll")                                                    \
            for (int ny = 0; ny < 4; ++ny)                                       \
                acc[mq][ny] = __builtin_amdgcn_mfma_f32_16x16x32_bf16(           \
                    SH[ny][kk], qhf[mq][kk], acc[mq][ny], 0, 0, 0);              \
    _Pragma("unroll")                                                            \
    for (int mq = 0; mq < 2; ++mq) {                                             \
        _Pragma("unroll")                                                        \
        for (int ny = 0; ny < 4; ++ny) {                                         \
            f32x4 v = acc[mq][ny];                                               \
            __builtin_nontemporal_store(v, reinterpret_cast<f32x4*>(             \
                out + ((size_t)(b * LL + rowBase + mq * 16 + ln)) * LL           \
                    + colBase_ + ny * 16 + kg * 4));                             \
            rmax[mq] = fmaxf(rmax[mq],                                           \
                       fmaxf(fmaxf(v[0], v[1]), fmaxf(v[2], v[3])));             \
        }                                                                        \
    }                                                                            \
} while (0)

    LOADY(yh0, yl0, 0);
    #pragma unroll
    for (int ct = 0; ct < 8; ct += 2) {
        if (ct + 1 < 8) LOADY(yh1, yl1, ct + 1);
        COMPSTORE(yh0, yl0, ct);
        if (ct + 2 < 8) LOADY(yh0, yl0, ct + 2);
        if (ct + 1 < 8) COMPSTORE(yh1, yl1, ct + 1);
    }

    // rmax[mq] covers this lane's q-row over this wave's cols. Combine kg groups
    // (lane bits 4,5), then the 4 waves via LDS.
    #pragma unroll
    for (int mq = 0; mq < 2; ++mq) {
        rmax[mq] = fmaxf(rmax[mq], __shfl_xor(rmax[mq], 16));
        rmax[mq] = fmaxf(rmax[mq], __shfl_xor(rmax[mq], 32));
    }

    __shared__ float smax[4][32];
    if (kg == 0) {
        smax[w][ln]      = rmax[0];
        smax[w][16 + ln] = rmax[1];
    }
    __syncthreads();
    if (t < 32) {
        const float v = fmaxf(fmaxf(smax[0][t], smax[1][t]),
                              fmaxf(smax[2][t], smax[3][t]));
        out[(size_t)BB * LL * LL + (size_t)b * LL + rowBase + t] = v;
    }
#undef LOADY
#undef COMPSTORE
}

extern "C" void kernel_launch(void* const* d_in, const int* in_sizes, int n_in,
                              void* d_out, int out_size, void* d_ws, size_t ws_size,
                              hipStream_t stream) {
    const float* q = (const float*)d_in[0];
    const float* y = (const float*)d_in[1];
    float* out     = (float*)d_out;
    ushort* ws     = (ushort*)d_ws;  // needs 8 MB

    norm_split_kernel<<<dim3(512, 2), dim3(256), 0, stream>>>(q, y, ws);
    att_mfma_kernel<<<dim3(512), dim3(256), 0, stream>>>(ws, out);
}

// Round 6
// 150.359 us; speedup vs baseline: 1.1640x; 1.1640x over previous
//
#include <hip/hip_runtime.h>

#define LL 2048
#define DD 64
#define BB 8
#define EPSF 1e-8f

#define NELEM ((size_t)BB * LL * DD)

typedef short bf16x8 __attribute__((ext_vector_type(8)));
typedef float f32x4 __attribute__((ext_vector_type(4)));
typedef float f32x8 __attribute__((ext_vector_type(8)));

__device__ __forceinline__ ushort f2bf(float f) {  // RNE float->bf16
    uint u = __float_as_uint(f);
    return (ushort)((u + 0x7fffu + ((u >> 16) & 1u)) >> 16);
}
__device__ __forceinline__ float bf2f(ushort h) {
    return __uint_as_float((uint)h << 16);
}

// Prepass: normalize y rows (fp32 math), store bf16 HI only. 32 rows/block.
__global__ __launch_bounds__(256) void norm_y_kernel(
    const float* __restrict__ y, ushort* __restrict__ yh) {
    const int row = blockIdx.x * 32 + (threadIdx.x >> 3);  // 0..16383
    const int oct = threadIdx.x & 7;
    const float* g = y + (size_t)row * DD;
    float4 v0 = *reinterpret_cast<const float4*>(g + oct * 4);
    float4 v1 = *reinterpret_cast<const float4*>(g + 32 + oct * 4);
    float ss = v0.x*v0.x + v0.y*v0.y + v0.z*v0.z + v0.w*v0.w
             + v1.x*v1.x + v1.y*v1.y + v1.z*v1.z + v1.w*v1.w;
    ss += __shfl_xor(ss, 1);
    ss += __shfl_xor(ss, 2);
    ss += __shfl_xor(ss, 4);
    const float sc = 1.0f / fmaxf(sqrtf(ss), EPSF);
    const size_t base = (size_t)row * DD + oct * 4;
    *reinterpret_cast<ushort4*>(yh + base) =
        make_ushort4(f2bf(v0.x*sc), f2bf(v0.y*sc), f2bf(v0.z*sc), f2bf(v0.w*sc));
    *reinterpret_cast<ushort4*>(yh + base + 32) =
        make_ushort4(f2bf(v1.x*sc), f2bf(v1.y*sc), f2bf(v1.z*sc), f2bf(v1.w*sc));
}

// One block = (batch b, 32-q-row strip); 2-D grid (x=strip, y=batch) -> batch-chunked
// linear order (R1 evidence: near-compulsory FETCH with this shape). 4 waves; wave w
// owns a 64-col slice of each 256-col step. q is normalized+hi/lo-split IN-KERNEL
// (strip-private). y is bf16 hi only; acc = yh*(qh+ql), error ~2^-12.
// MFMA operands swapped (A=y M-side, B=q N-side): D col=lane&15 = q row,
// row=kg*4+j = y col -> f32x4 stores along output cols, per-lane row-max.
__global__ __launch_bounds__(256, 3) void att_mfma_kernel(
    const float* __restrict__ q, const ushort* __restrict__ yhg,
    float* __restrict__ out) {
    const int b       = blockIdx.y;
    const int rowBase = blockIdx.x * 32;
    const int t  = threadIdx.x;
    const int w  = t >> 6;
    const int l  = t & 63;
    const int ln = l & 15;   // q row within 16-subtile
    const int kg = l >> 4;   // k-group; in D: y-col group of 4

    // ---- inline q normalize + hi/lo split into fragments ----
    bf16x8 qhf[2][2], qlf[2][2];
    #pragma unroll
    for (int mq = 0; mq < 2; ++mq) {
        f32x8 v[2];
        #pragma unroll
        for (int kk = 0; kk < 2; ++kk)
            v[kk] = *reinterpret_cast<const f32x8*>(
                q + ((size_t)(b * LL + rowBase + mq * 16 + ln)) * DD + kk * 32 + kg * 8);
        float ss = 0.f;
        #pragma unroll
        for (int kk = 0; kk < 2; ++kk)
            #pragma unroll
            for (int j = 0; j < 8; ++j) ss += v[kk][j] * v[kk][j];
        ss += __shfl_xor(ss, 16);   // combine the 4 kg chunks of this row
        ss += __shfl_xor(ss, 32);
        const float sc = 1.0f / fmaxf(sqrtf(ss), EPSF);
        #pragma unroll
        for (int kk = 0; kk < 2; ++kk)
            #pragma unroll
            for (int j = 0; j < 8; ++j) {
                const float f = v[kk][j] * sc;
                const ushort h = f2bf(f);
                qhf[mq][kk][j] = (short)h;
                qlf[mq][kk][j] = (short)f2bf(f - bf2f(h));
            }
    }

    float rmax[2] = {-1e30f, -1e30f};  // per-lane: q row = rowBase + mq*16 + ln

    bf16x8 yh0[4][2], yh1[4][2];

#define LOADY(DH, CT) do {                                                       \
    const int colBase_ = (CT) * 256 + w * 64;                                    \
    _Pragma("unroll")                                                            \
    for (int ny = 0; ny < 4; ++ny)                                               \
        _Pragma("unroll")                                                        \
        for (int kk = 0; kk < 2; ++kk)                                           \
            DH[ny][kk] = *reinterpret_cast<const bf16x8*>(                       \
                yhg + ((size_t)(b * LL + colBase_ + ny * 16 + ln)) * DD          \
                    + kk * 32 + kg * 8);                                         \
} while (0)

#define COMPSTORE(SH, CT) do {                                                   \
    const int colBase_ = (CT) * 256 + w * 64;                                    \
    f32x4 acc[2][4];                                                             \
    _Pragma("unroll")                                                            \
    for (int mq = 0; mq < 2; ++mq)                                               \
        _Pragma("unroll")                                                        \
        for (int ny = 0; ny < 4; ++ny)                                           \
            acc[mq][ny] = (f32x4){0.f, 0.f, 0.f, 0.f};                           \
    _Pragma("unroll")                                                            \
    for (int kk = 0; kk < 2; ++kk)                                               \
        _Pragma("unroll")                                                        \
        for (int mq = 0; mq < 2; ++mq)                                           \
            _Pragma("unroll")                                                    \
            for (int ny = 0; ny < 4; ++ny)                                       \
                acc[mq][ny] = __builtin_amdgcn_mfma_f32_16x16x32_bf16(           \
                    SH[ny][kk], qlf[mq][kk], acc[mq][ny], 0, 0, 0);              \
    _Pragma("unroll")                                                            \
    for (int kk = 0; kk < 2; ++kk)                                               \
        _Pragma("unroll")                                                        \
        for (int mq = 0; mq < 2; ++mq)                                           \
            _Pragma("unroll")                                                    \
            for (int ny = 0; ny < 4; ++ny)                                       \
                acc[mq][ny] = __builtin_amdgcn_mfma_f32_16x16x32_bf16(           \
                    SH[ny][kk], qhf[mq][kk], acc[mq][ny], 0, 0, 0);              \
    _Pragma("unroll")                                                            \
    for (int mq = 0; mq < 2; ++mq) {                                             \
        _Pragma("unroll")                                                        \
        for (int ny = 0; ny < 4; ++ny) {                                         \
            f32x4 v = acc[mq][ny];                                               \
            *reinterpret_cast<f32x4*>(                                           \
                out + ((size_t)(b * LL + rowBase + mq * 16 + ln)) * LL           \
                    + colBase_ + ny * 16 + kg * 4) = v;                          \
            rmax[mq] = fmaxf(rmax[mq],                                           \
                       fmaxf(fmaxf(v[0], v[1]), fmaxf(v[2], v[3])));             \
        }                                                                        \
    }                                                                            \
} while (0)

    LOADY(yh0, 0);
    #pragma unroll
    for (int ct = 0; ct < 8; ct += 2) {
        if (ct + 1 < 8) LOADY(yh1, ct + 1);
        COMPSTORE(yh0, ct);
        if (ct + 2 < 8) LOADY(yh0, ct + 2);
        if (ct + 1 < 8) COMPSTORE(yh1, ct + 1);
    }

    // rmax[mq] covers this lane's q-row over this wave's cols. Combine kg groups
    // (lane bits 4,5), then the 4 waves via LDS.
    #pragma unroll
    for (int mq = 0; mq < 2; ++mq) {
        rmax[mq] = fmaxf(rmax[mq], __shfl_xor(rmax[mq], 16));
        rmax[mq] = fmaxf(rmax[mq], __shfl_xor(rmax[mq], 32));
    }

    __shared__ float smax[4][32];
    if (kg == 0) {
        smax[w][ln]      = rmax[0];
        smax[w][16 + ln] = rmax[1];
    }
    __syncthreads();
    if (t < 32) {
        const float v = fmaxf(fmaxf(smax[0][t], smax[1][t]),
                              fmaxf(smax[2][t], smax[3][t]));
        out[(size_t)BB * LL * LL + (size_t)b * LL + rowBase + t] = v;
    }
#undef LOADY
#undef COMPSTORE
}

extern "C" void kernel_launch(void* const* d_in, const int* in_sizes, int n_in,
                              void* d_out, int out_size, void* d_ws, size_t ws_size,
                              hipStream_t stream) {
    const float* q = (const float*)d_in[0];
    const float* y = (const float*)d_in[1];
    float* out     = (float*)d_out;
    ushort* yh     = (ushort*)d_ws;  // needs 4 MB

    norm_y_kernel<<<dim3(512), dim3(256), 0, stream>>>(y, yh);
    att_mfma_kernel<<<dim3(LL / 32, BB), dim3(256), 0, stream>>>(q, yh, out);
}